// Round 1
// baseline (2822.473 us; speedup 1.0000x reference)
//
#include <hip/hip_runtime.h>
#include <math.h>

// Problem constants (from reference): N=100000 nodes, D=128 features, E=1600000 edges.
// Inputs (in order): t(1), x(N*D f32), edge_index(2*E int), edge_weight(E f32),
//                    x0(N*D f32), alpha_train(1), beta_train(1), source_train(1)
// Output: f32 [N, D]
//
// f = alpha*(Ax - x) + beta*(-(x-1)*x) + clip(src*x0,-1,1)*0.1
//   where Ax[row] += w[e] * x[col[e]]
//
// Round 1 strategy: correctness-first baseline.
//   kernel 1: out = -alpha*x - beta*(x-1)*x + clip(src*x0,-1,1)*0.1    (float4 streaming)
//   kernel 2: edge-parallel scatter: atomicAdd(out[row], alpha*w*x[col])
//             32 lanes per edge, float4 per lane (D=128 -> 32*4).

#define D_FEAT 128

__device__ __forceinline__ float sigmoid_f(float v) {
    return 1.0f / (1.0f + __expf(-v));
}

__global__ void base_kernel(const float* __restrict__ x,
                            const float* __restrict__ x0,
                            const float* __restrict__ alpha_p,
                            const float* __restrict__ beta_p,
                            const float* __restrict__ src_p,
                            float* __restrict__ out,
                            int total4) {
    const float alpha = sigmoid_f(alpha_p[0]) * 0.1f;
    const float beta  = sigmoid_f(beta_p[0]) * 0.1f;
    const float src   = src_p[0];

    int i = blockIdx.x * blockDim.x + threadIdx.x;
    if (i >= total4) return;

    const float4* x4  = (const float4*)x;
    const float4* x04 = (const float4*)x0;
    float4 xv  = x4[i];
    float4 x0v = x04[i];

    float4 o;
    {
        float xs[4] = {xv.x, xv.y, xv.z, xv.w};
        float zs[4] = {x0v.x, x0v.y, x0v.z, x0v.w};
        float os[4];
#pragma unroll
        for (int k = 0; k < 4; ++k) {
            float reaction = -(xs[k] - 1.0f) * xs[k];
            float st = src * zs[k];
            st = fminf(fmaxf(st, -1.0f), 1.0f);
            os[k] = -alpha * xs[k] + beta * reaction + st * 0.1f;
        }
        o.x = os[0]; o.y = os[1]; o.z = os[2]; o.w = os[3];
    }
    ((float4*)out)[i] = o;
}

__global__ void scatter_kernel(const float* __restrict__ x,
                               const int* __restrict__ rows,
                               const int* __restrict__ cols,
                               const float* __restrict__ w,
                               const float* __restrict__ alpha_p,
                               float* __restrict__ out,
                               int E) {
    const float alpha = sigmoid_f(alpha_p[0]) * 0.1f;

    int tid  = blockIdx.x * blockDim.x + threadIdx.x;
    int lane = tid & 31;          // feature-quad index: 32 quads of float4 = 128
    int e    = tid >> 5;
    if (e >= E) return;

    int   r  = rows[e];
    int   c  = cols[e];
    float we = w[e] * alpha;

    const float4* xr = (const float4*)(x + (long long)c * D_FEAT);
    float4 v = xr[lane];

    float* o = out + (long long)r * D_FEAT + lane * 4;
    atomicAdd(o + 0, we * v.x);
    atomicAdd(o + 1, we * v.y);
    atomicAdd(o + 2, we * v.z);
    atomicAdd(o + 3, we * v.w);
}

extern "C" void kernel_launch(void* const* d_in, const int* in_sizes, int n_in,
                              void* d_out, int out_size, void* d_ws, size_t ws_size,
                              hipStream_t stream) {
    // input order: t, x, edge_index, edge_weight, x0, alpha_train, beta_train, source_train
    const float* x   = (const float*)d_in[1];
    const int*   ei  = (const int*)d_in[2];
    const float* ew  = (const float*)d_in[3];
    const float* x0  = (const float*)d_in[4];
    const float* alp = (const float*)d_in[5];
    const float* bet = (const float*)d_in[6];
    const float* src = (const float*)d_in[7];
    float* out = (float*)d_out;

    const int E = in_sizes[3];            // edge count (edge_weight is [E])
    const int total = out_size;           // N * D
    const int total4 = total / 4;

    // edge_index is [2, E]: row = ei[e], col = ei[E + e]
    const int* rows = ei;
    const int* cols = ei + E;

    {
        int block = 256;
        int grid = (total4 + block - 1) / block;
        base_kernel<<<grid, block, 0, stream>>>(x, x0, alp, bet, src, out, total4);
    }
    {
        long long threads = (long long)E * 32;
        int block = 256;
        long long grid = (threads + block - 1) / block;
        scatter_kernel<<<(int)grid, block, 0, stream>>>(x, rows, cols, ew, alp, out, E);
    }
}

// Round 2
// 464.933 us; speedup vs baseline: 6.0707x; 6.0707x over previous
//
#include <hip/hip_runtime.h>
#include <math.h>

// N=100000 nodes, D=128 feats, E=1600000 edges.
// f = alpha*(Ax - x) + beta*(-(x-1)*x) + clip(src*x0,-1,1)*0.1,  Ax[row] += w*x[col]
//
// R2 strategy: device-built CSR (count sort by row) + node-parallel gather.
// Removes the 204.8M f32 output atomics (R1: 3.28 GB write-through, 2677 us).
//   K0 zero counts -> K1 count -> K2 chunk scan -> K3 chunk-total scan ->
//   K4 apply offsets (+cursor copy) -> K5 fill col_s/w_s -> K6 gather+epilogue

#define D_FEAT 128
#define SCAN_CHUNK 2048   // 256 threads x 8 elements

__device__ __forceinline__ float sigmoid_f(float v) {
    return 1.0f / (1.0f + __expf(-v));
}

__global__ void zero_kernel(int* __restrict__ p, int n) {
    int i = blockIdx.x * blockDim.x + threadIdx.x;
    if (i < n) p[i] = 0;
}

__global__ void count_kernel(const int* __restrict__ rows, int* __restrict__ cnt, int E) {
    int i = blockIdx.x * blockDim.x + threadIdx.x;
    int stride = gridDim.x * blockDim.x;
    for (int e = i; e < E; e += stride) {
        atomicAdd(&cnt[rows[e]], 1);
    }
}

// Per-chunk exclusive scan: each block scans SCAN_CHUNK elements of cnt into off,
// writes chunk total to blksum[chunk].
__global__ void scan_chunk_kernel(const int* __restrict__ cnt, int* __restrict__ off,
                                  int* __restrict__ blksum, int N) {
    __shared__ int lds[256];
    int tid = threadIdx.x;
    int chunk = blockIdx.x;
    int base = chunk * SCAN_CHUNK + tid * 8;

    int v[8], ex[8];
    int run = 0;
#pragma unroll
    for (int k = 0; k < 8; ++k) {
        int idx = base + k;
        v[k] = (idx < N) ? cnt[idx] : 0;
        ex[k] = run;
        run += v[k];
    }
    lds[tid] = run;
    __syncthreads();
    // Hillis-Steele inclusive scan over 256 thread sums
    for (int d = 1; d < 256; d <<= 1) {
        int t = (tid >= d) ? lds[tid - d] : 0;
        __syncthreads();
        lds[tid] += t;
        __syncthreads();
    }
    int excl = lds[tid] - run;   // exclusive prefix of this thread's sum
#pragma unroll
    for (int k = 0; k < 8; ++k) {
        int idx = base + k;
        if (idx < N) off[idx] = excl + ex[k];
    }
    if (tid == 255) blksum[chunk] = lds[255];
}

// Exclusive scan of chunk totals (numChunks ~ 49) — single thread is fine.
__global__ void scan_tot_kernel(int* __restrict__ blksum, int numChunks) {
    if (threadIdx.x == 0 && blockIdx.x == 0) {
        int run = 0;
        for (int c = 0; c < numChunks; ++c) {
            int t = blksum[c];
            blksum[c] = run;
            run += t;
        }
    }
}

__global__ void apply_off_kernel(int* __restrict__ off, int* __restrict__ cursor,
                                 const int* __restrict__ blksum, int N, int E) {
    int i = blockIdx.x * blockDim.x + threadIdx.x;
    int stride = gridDim.x * blockDim.x;
    for (int j = i; j < N; j += stride) {
        int o = off[j] + blksum[j / SCAN_CHUNK];
        off[j] = o;
        cursor[j] = o;
    }
    if (i == 0) off[N] = E;
}

__global__ void fill_kernel(const int* __restrict__ rows, const int* __restrict__ cols,
                            const float* __restrict__ w, const float* __restrict__ alpha_p,
                            int* __restrict__ cursor,
                            int* __restrict__ col_s, float* __restrict__ w_s, int E) {
    const float alpha = sigmoid_f(alpha_p[0]) * 0.1f;
    int i = blockIdx.x * blockDim.x + threadIdx.x;
    int stride = gridDim.x * blockDim.x;
    for (int e = i; e < E; e += stride) {
        int r = rows[e];
        int p = atomicAdd(&cursor[r], 1);
        col_s[p] = cols[e];
        w_s[p] = w[e] * alpha;   // pre-scale by alpha
    }
}

// One 64-lane wave per row. Lanes split into two halves, each half processes
// alternate edges with float4 (32 quads = 128 feats); halves combined via shfl_xor.
// Full elementwise epilogue folded into the single coalesced write.
__global__ void gather_kernel(const float* __restrict__ x,
                              const float* __restrict__ x0,
                              const int* __restrict__ off,
                              const int* __restrict__ col_s,
                              const float* __restrict__ w_s,
                              const float* __restrict__ alpha_p,
                              const float* __restrict__ beta_p,
                              const float* __restrict__ src_p,
                              float* __restrict__ out, int N) {
    const float alpha = sigmoid_f(alpha_p[0]) * 0.1f;
    const float beta  = sigmoid_f(beta_p[0]) * 0.1f;
    const float src   = src_p[0];

    int gtid = blockIdx.x * blockDim.x + threadIdx.x;
    int row  = gtid >> 6;
    if (row >= N) return;
    int lane  = threadIdx.x & 63;
    int half  = lane >> 5;    // 0/1: which edge of the pair
    int flane = lane & 31;    // feature quad index

    int start = off[row];
    int end   = off[row + 1];

    const float4* x4 = (const float4*)x;
    float4 acc = make_float4(0.f, 0.f, 0.f, 0.f);
    for (int j = start + half; j < end; j += 2) {
        int   c  = col_s[j];   // broadcast within half-wave
        float wv = w_s[j];
        float4 v = x4[(long long)c * 32 + flane];
        acc.x += wv * v.x;
        acc.y += wv * v.y;
        acc.z += wv * v.z;
        acc.w += wv * v.w;
    }
    // combine the two half-wave partials
    acc.x += __shfl_xor(acc.x, 32);
    acc.y += __shfl_xor(acc.y, 32);
    acc.z += __shfl_xor(acc.z, 32);
    acc.w += __shfl_xor(acc.w, 32);

    if (half == 0) {
        long long base = (long long)row * 32 + flane;
        float4 xv  = x4[base];
        float4 x0v = ((const float4*)x0)[base];
        float xs[4]  = {xv.x, xv.y, xv.z, xv.w};
        float zs[4]  = {x0v.x, x0v.y, x0v.z, x0v.w};
        float as[4]  = {acc.x, acc.y, acc.z, acc.w};
        float os[4];
#pragma unroll
        for (int k = 0; k < 4; ++k) {
            float reaction = -(xs[k] - 1.0f) * xs[k];
            float st = fminf(fmaxf(src * zs[k], -1.0f), 1.0f);
            os[k] = as[k] - alpha * xs[k] + beta * reaction + st * 0.1f;
        }
        ((float4*)out)[base] = make_float4(os[0], os[1], os[2], os[3]);
    }
}

extern "C" void kernel_launch(void* const* d_in, const int* in_sizes, int n_in,
                              void* d_out, int out_size, void* d_ws, size_t ws_size,
                              hipStream_t stream) {
    const float* x   = (const float*)d_in[1];
    const int*   ei  = (const int*)d_in[2];
    const float* ew  = (const float*)d_in[3];
    const float* x0  = (const float*)d_in[4];
    const float* alp = (const float*)d_in[5];
    const float* bet = (const float*)d_in[6];
    const float* src = (const float*)d_in[7];
    float* out = (float*)d_out;

    const int E = in_sizes[3];
    const int N = out_size / D_FEAT;
    const int* rows = ei;
    const int* cols = ei + E;

    const int numChunks = (N + SCAN_CHUNK - 1) / SCAN_CHUNK;

    // workspace layout (16B-aligned regions)
    char* ws = (char*)d_ws;
    int* cnt    = (int*)ws;                       ws += ((size_t)N * 4 + 15) & ~15ull;
    int* off    = (int*)ws;                       ws += ((size_t)(N + 1) * 4 + 15) & ~15ull;
    int* cursor = (int*)ws;                       ws += ((size_t)N * 4 + 15) & ~15ull;
    int* blksum = (int*)ws;                       ws += ((size_t)numChunks * 4 + 15) & ~15ull;
    int*   col_s = (int*)ws;                      ws += ((size_t)E * 4 + 15) & ~15ull;
    float* w_s   = (float*)ws;                    ws += ((size_t)E * 4 + 15) & ~15ull;

    zero_kernel<<<(N + 255) / 256, 256, 0, stream>>>(cnt, N);
    count_kernel<<<1024, 256, 0, stream>>>(rows, cnt, E);
    scan_chunk_kernel<<<numChunks, 256, 0, stream>>>(cnt, off, blksum, N);
    scan_tot_kernel<<<1, 64, 0, stream>>>(blksum, numChunks);
    apply_off_kernel<<<(N + 255) / 256, 256, 0, stream>>>(off, cursor, blksum, N, E);
    fill_kernel<<<1024, 256, 0, stream>>>(rows, cols, ew, alp, cursor, col_s, w_s, E);
    {
        long long threads = (long long)N * 64;
        int grid = (int)((threads + 255) / 256);
        gather_kernel<<<grid, 256, 0, stream>>>(x, x0, off, col_s, w_s,
                                                alp, bet, src, out, N);
    }
}

// Round 3
// 451.684 us; speedup vs baseline: 6.2488x; 1.0293x over previous
//
#include <hip/hip_runtime.h>
#include <math.h>

// N=100000 nodes, D=128 feats, E=1600000 edges.
// f = alpha*(Ax - x) + beta*(-(x-1)*x) + clip(src*x0,-1,1)*0.1,  Ax[row] += w*x[col]
//
// R3: faster device CSR build + higher-MLP gather.
//  - count: int4 edge reads, 4 atomics/thread
//  - scan_chunk (2048/block) -> wave-parallel chunk-total scan -> apply_off
//  - fill: atomicAdd directly on off[] (start->end), packed int2 (col, w*alpha) store
//  - gather: one wave/row, 2 half-waves x unroll2 = 4 x-rows in flight, epilogue fused

#define D_FEAT 128
#define SCAN_CHUNK 2048   // 256 threads x 8 elements

__device__ __forceinline__ float sigmoid_f(float v) {
    return 1.0f / (1.0f + __expf(-v));
}

__global__ void zero_kernel(int* __restrict__ p, int n) {
    int i = blockIdx.x * blockDim.x + threadIdx.x;
    if (i < n) p[i] = 0;
}

// 4 edges per thread via int4 load.
__global__ void count_kernel(const int* __restrict__ rows, int* __restrict__ cnt, int E4) {
    int i = blockIdx.x * blockDim.x + threadIdx.x;
    if (i >= E4) return;
    int4 r = ((const int4*)rows)[i];
    atomicAdd(&cnt[r.x], 1);
    atomicAdd(&cnt[r.y], 1);
    atomicAdd(&cnt[r.z], 1);
    atomicAdd(&cnt[r.w], 1);
}

// Per-chunk exclusive scan: block scans SCAN_CHUNK elems of cnt into off,
// writes chunk total to blksum[chunk].
__global__ void scan_chunk_kernel(const int* __restrict__ cnt, int* __restrict__ off,
                                  int* __restrict__ blksum, int N) {
    __shared__ int lds[256];
    int tid = threadIdx.x;
    int chunk = blockIdx.x;
    int base = chunk * SCAN_CHUNK + tid * 8;

    int v[8], ex[8];
    int run = 0;
#pragma unroll
    for (int k = 0; k < 8; ++k) {
        int idx = base + k;
        v[k] = (idx < N) ? cnt[idx] : 0;
        ex[k] = run;
        run += v[k];
    }
    lds[tid] = run;
    __syncthreads();
    for (int d = 1; d < 256; d <<= 1) {
        int t = (tid >= d) ? lds[tid - d] : 0;
        __syncthreads();
        lds[tid] += t;
        __syncthreads();
    }
    int excl = lds[tid] - run;
#pragma unroll
    for (int k = 0; k < 8; ++k) {
        int idx = base + k;
        if (idx < N) off[idx] = excl + ex[k];
    }
    if (tid == 255) blksum[chunk] = lds[255];
}

// One-wave exclusive scan of chunk totals (handles any numChunks via 64-wide tiles).
__global__ void scan_tot_kernel(int* __restrict__ blksum, int numChunks) {
    int lane = threadIdx.x;   // 64 threads
    int carry = 0;
    for (int base = 0; base < numChunks; base += 64) {
        int idx = base + lane;
        int v = (idx < numChunks) ? blksum[idx] : 0;
        int incl = v;
#pragma unroll
        for (int d = 1; d < 64; d <<= 1) {
            int t = __shfl_up(incl, d);
            if (lane >= d) incl += t;
        }
        int tile_total = __shfl(incl, 63);
        int excl = incl - v + carry;
        if (idx < numChunks) blksum[idx] = excl;
        carry += tile_total;
    }
}

__global__ void apply_off_kernel(int* __restrict__ off, const int* __restrict__ blksum,
                                 int N) {
    int j = blockIdx.x * blockDim.x + threadIdx.x;
    if (j < N) off[j] += blksum[j >> 11];   // SCAN_CHUNK == 2048
}

// 4 edges per thread; atomicAdd directly on off[] (turns start offsets into end
// offsets); packed (col, w*alpha) 8B store.
__global__ void fill_kernel(const int* __restrict__ rows, const int* __restrict__ cols,
                            const float* __restrict__ w, const float* __restrict__ alpha_p,
                            int* __restrict__ off,
                            int2* __restrict__ col_w, int E4) {
    const float alpha = sigmoid_f(alpha_p[0]) * 0.1f;
    int i = blockIdx.x * blockDim.x + threadIdx.x;
    if (i >= E4) return;
    int4   r = ((const int4*)rows)[i];
    int4   c = ((const int4*)cols)[i];
    float4 ww = ((const float4*)w)[i];

    int p0 = atomicAdd(&off[r.x], 1);
    col_w[p0] = make_int2(c.x, __float_as_int(ww.x * alpha));
    int p1 = atomicAdd(&off[r.y], 1);
    col_w[p1] = make_int2(c.y, __float_as_int(ww.y * alpha));
    int p2 = atomicAdd(&off[r.z], 1);
    col_w[p2] = make_int2(c.z, __float_as_int(ww.z * alpha));
    int p3 = atomicAdd(&off[r.w], 1);
    col_w[p3] = make_int2(c.w, __float_as_int(ww.w * alpha));
}

// One 64-lane wave per row; two half-waves each unrolled x2 -> 4 x-row loads in
// flight. After fill, off[r] = end of row r; start = off[r-1] (0 for r=0).
__global__ void gather_kernel(const float* __restrict__ x,
                              const float* __restrict__ x0,
                              const int* __restrict__ off,
                              const int2* __restrict__ col_w,
                              const float* __restrict__ alpha_p,
                              const float* __restrict__ beta_p,
                              const float* __restrict__ src_p,
                              float* __restrict__ out, int N) {
    const float alpha = sigmoid_f(alpha_p[0]) * 0.1f;
    const float beta  = sigmoid_f(beta_p[0]) * 0.1f;
    const float src   = src_p[0];

    int gtid = blockIdx.x * blockDim.x + threadIdx.x;
    int row  = gtid >> 6;
    if (row >= N) return;
    int lane  = threadIdx.x & 63;
    int half  = lane >> 5;
    int flane = lane & 31;

    int start = (row == 0) ? 0 : off[row - 1];
    int end   = off[row];

    const float4* x4 = (const float4*)x;
    float4 a0 = make_float4(0.f, 0.f, 0.f, 0.f);
    float4 a1 = make_float4(0.f, 0.f, 0.f, 0.f);

    int j = start + half;
    // unroll 2: edges j and j+2 for this half
    for (; j + 2 < end; j += 4) {
        int2 cw0 = col_w[j];
        int2 cw1 = col_w[j + 2];
        float4 v0 = x4[(long long)cw0.x * 32 + flane];
        float4 v1 = x4[(long long)cw1.x * 32 + flane];
        float w0 = __int_as_float(cw0.y);
        float w1 = __int_as_float(cw1.y);
        a0.x += w0 * v0.x; a0.y += w0 * v0.y; a0.z += w0 * v0.z; a0.w += w0 * v0.w;
        a1.x += w1 * v1.x; a1.y += w1 * v1.y; a1.z += w1 * v1.z; a1.w += w1 * v1.w;
    }
    if (j < end) {
        int2 cw = col_w[j];
        float4 v = x4[(long long)cw.x * 32 + flane];
        float wv = __int_as_float(cw.y);
        a0.x += wv * v.x; a0.y += wv * v.y; a0.z += wv * v.z; a0.w += wv * v.w;
    }
    float4 acc;
    acc.x = a0.x + a1.x; acc.y = a0.y + a1.y;
    acc.z = a0.z + a1.z; acc.w = a0.w + a1.w;

    acc.x += __shfl_xor(acc.x, 32);
    acc.y += __shfl_xor(acc.y, 32);
    acc.z += __shfl_xor(acc.z, 32);
    acc.w += __shfl_xor(acc.w, 32);

    if (half == 0) {
        long long base = (long long)row * 32 + flane;
        float4 xv  = x4[base];
        float4 x0v = ((const float4*)x0)[base];
        float xs[4]  = {xv.x, xv.y, xv.z, xv.w};
        float zs[4]  = {x0v.x, x0v.y, x0v.z, x0v.w};
        float as[4]  = {acc.x, acc.y, acc.z, acc.w};
        float os[4];
#pragma unroll
        for (int k = 0; k < 4; ++k) {
            float reaction = -(xs[k] - 1.0f) * xs[k];
            float st = fminf(fmaxf(src * zs[k], -1.0f), 1.0f);
            os[k] = as[k] - alpha * xs[k] + beta * reaction + st * 0.1f;
        }
        ((float4*)out)[base] = make_float4(os[0], os[1], os[2], os[3]);
    }
}

extern "C" void kernel_launch(void* const* d_in, const int* in_sizes, int n_in,
                              void* d_out, int out_size, void* d_ws, size_t ws_size,
                              hipStream_t stream) {
    const float* x   = (const float*)d_in[1];
    const int*   ei  = (const int*)d_in[2];
    const float* ew  = (const float*)d_in[3];
    const float* x0  = (const float*)d_in[4];
    const float* alp = (const float*)d_in[5];
    const float* bet = (const float*)d_in[6];
    const float* src = (const float*)d_in[7];
    float* out = (float*)d_out;

    const int E = in_sizes[3];
    const int N = out_size / D_FEAT;
    const int* rows = ei;
    const int* cols = ei + E;

    const int numChunks = (N + SCAN_CHUNK - 1) / SCAN_CHUNK;
    const int E4 = E / 4;           // E divisible by 4 here (1.6M)

    char* ws = (char*)d_ws;
    int* cnt    = (int*)ws;   ws += ((size_t)N * 4 + 15) & ~15ull;
    int* off    = (int*)ws;   ws += ((size_t)N * 4 + 15) & ~15ull;
    int* blksum = (int*)ws;   ws += ((size_t)numChunks * 4 + 15) & ~15ull;
    int2* col_w = (int2*)ws;  ws += ((size_t)E * 8 + 15) & ~15ull;

    zero_kernel<<<(N + 255) / 256, 256, 0, stream>>>(cnt, N);
    count_kernel<<<(E4 + 255) / 256, 256, 0, stream>>>(rows, cnt, E4);
    scan_chunk_kernel<<<numChunks, 256, 0, stream>>>(cnt, off, blksum, N);
    scan_tot_kernel<<<1, 64, 0, stream>>>(blksum, numChunks);
    apply_off_kernel<<<(N + 255) / 256, 256, 0, stream>>>(off, blksum, N);
    fill_kernel<<<(E4 + 255) / 256, 256, 0, stream>>>(rows, cols, ew, alp, off, col_w, E4);
    {
        long long threads = (long long)N * 64;
        int grid = (int)((threads + 255) / 256);
        gather_kernel<<<grid, 256, 0, stream>>>(x, x0, off, col_w, alp, bet, src, out, N);
    }
}